// Round 2
// baseline (292.671 us; speedup 1.0000x reference)
//
#include <hip/hip_runtime.h>
#include <hip/hip_bf16.h>

// Transposed conv (full conv): out[b,p,q,co] = sum_{kh,kw,ci} in[b,p-kh,q-kw,ci]*K[ci,co,kh,kw]
// B=8 H=W=256 C=64, out 8x258x258x64 fp32. bf16 MFMA path.
//
// R2 design (resubmit — R2 bench was an infra failure, kernel never ran):
// 512-thr block, 16x16 output tile (was 32x16). Input patch 18x18x64 bf16
// in LDS = 41472 B -> 3 blocks/CU (was 2), 24 waves/CU. Each wave: 2 output rows x
// 64 co, acc[2][4] (32 AGPR) so 6 waves/SIMD fit the VGPR budget
// (__launch_bounds__(512,6)). Staging: batch-issue 3 granule loads to registers,
// then convert+ds_write -> ~3x deeper MLP than the old unroll-1 chain.
// Weight path unchanged: pre-swizzled fragments in d_ws, read from global (L1/L2-hot).

#define OH 258
#define OW 258

typedef __bf16 bf16x8 __attribute__((ext_vector_type(8)));
typedef float  f32x4  __attribute__((ext_vector_type(4)));

// ws layout: wsW[((tap*2+s)*64+co)*32 + c] = K[ci=32s+c][co][kh][kw], tap=kh*3+kw
// => fragment (tap,s,nt) is a contiguous 1KB block; lane (ml,h) reads ml*32+h*8.
__global__ void prep_w_kernel(const float* __restrict__ k, __bf16* __restrict__ wsW) {
    int i = blockIdx.x * 256 + threadIdx.x;            // [0, 36864)
    int c  = i & 31;
    int co = (i >> 5) & 63;
    int st = i >> 11;                                  // [0,18)
    int s   = st & 1;
    int tap = st >> 1;
    int kh = tap / 3, kw = tap % 3;
    float v = k[(s * 32 + c) * 576 + co * 9 + kh * 3 + kw];
    wsW[i] = (__bf16)v;
}

__global__ __launch_bounds__(512, 6)
void tconv_kernel(const float* __restrict__ in, const __bf16* __restrict__ wsW,
                  float* __restrict__ out) {
    // input patch [pix=18*18][64ci] bf16, 16B granules XOR-swizzled by pix&7
    __shared__ __bf16 lds_in[324 * 64];   // 41472 B -> 3 blocks/CU

    const int tid = threadIdx.x;
    const int b  = blockIdx.z;
    const int p0 = blockIdx.y * 16;
    const int q0 = blockIdx.x * 16;

    // ---- stage input rows p0-2..p0+15, cols q0-2..q0+15; zero-pad OOB.
    // 18*18*8 = 2592 granules (granule = 8 ci = 16B bf16 = 32B fp32), 512 thr
    // -> <=6 granules/thread, processed in 2 batches of 3 (loads batched for MLP).
    #pragma unroll 1
    for (int kk = 0; kk < 6; kk += 3) {
        f32x4 v0[3], v1[3];
        int soff[3];
        #pragma unroll
        for (int u = 0; u < 3; ++u) {
            const int k = kk + u;
            const int it = tid + k * 512;
            const bool act = (k < 5) || (tid < 32);    // it < 2592 (k compile-time)
            int pix = it >> 3, c8 = it & 7;
            int r = pix / 18, c = pix - r * 18;
            int ip = p0 - 2 + r, iq = q0 - 2 + c;
            f32x4 z = {0.f, 0.f, 0.f, 0.f};
            v0[u] = z; v1[u] = z;
            if (act && (unsigned)ip < 256u && (unsigned)iq < 256u) {
                const float* g = in + (((size_t)b * 256 + ip) * 256 + iq) * 64 + c8 * 8;
                v0[u] = *(const f32x4*)g;
                v1[u] = *(const f32x4*)(g + 4);
            }
            soff[u] = pix * 64 + ((c8 ^ (pix & 7)) * 8);
        }
        #pragma unroll
        for (int u = 0; u < 3; ++u) {
            const int k = kk + u;
            const bool act = (k < 5) || (tid < 32);
            if (act) {
                bf16x8 w;
                w[0]=(__bf16)v0[u][0]; w[1]=(__bf16)v0[u][1]; w[2]=(__bf16)v0[u][2]; w[3]=(__bf16)v0[u][3];
                w[4]=(__bf16)v1[u][0]; w[5]=(__bf16)v1[u][1]; w[6]=(__bf16)v1[u][2]; w[7]=(__bf16)v1[u][3];
                *(bf16x8*)&lds_in[soff[u]] = w;
            }
        }
    }
    __syncthreads();   // the ONLY barrier

    const int wv = tid >> 6, lane = tid & 63;
    const int ml = lane & 15, h = lane >> 4;           // A: m=ml; B: n=ml; k-quad=h
    const int woff = ml * 32 + h * 8;                  // B-frag lane offset (elems)
    const int rbase = wv * 2;                          // wave's 2 rows of the 16

    f32x4 acc[2][4] = {};   // mt = output row within wave's 2; nt = co/16

    #pragma unroll 1
    for (int tap = 0; tap < 9; ++tap) {
        const int kh = tap / 3, kw = tap - kh * 3;
        const __bf16* wt = wsW + tap * 4096;
        #pragma unroll
        for (int s = 0; s < 2; ++s) {
            bf16x8 bfr[4];
            #pragma unroll
            for (int nt = 0; nt < 4; ++nt)
                bfr[nt] = *(const bf16x8*)(wt + s * 2048 + nt * 512 + woff);
            const int j = s * 4 + h;                   // 16B granule index within pixel
            #pragma unroll
            for (int mt = 0; mt < 2; ++mt) {
                int row = rbase + mt + 2 - kh;         // patch row, always in [0,18)
                int pix = row * 18 + (2 - kw) + ml;    // m-tile = one output row (16 q)
                bf16x8 afr = *(const bf16x8*)&lds_in[pix * 64 + ((j ^ (pix & 7)) * 8)];
                #pragma unroll
                for (int nt = 0; nt < 4; ++nt)
                    acc[mt][nt] = __builtin_amdgcn_mfma_f32_16x16x32_bf16(
                        afr, bfr[nt], acc[mt][nt], 0, 0, 0);
            }
        }
    }

    // ---- epilogue: D layout col(co)=ml, row(q within row-tile)=h*4+reg
    #pragma unroll
    for (int mt = 0; mt < 2; ++mt) {
        int p = p0 + rbase + mt;
        if (p < OH) {
            int qb = q0 + h * 4;
            #pragma unroll
            for (int nt = 0; nt < 4; ++nt) {
                float* op = out + (((size_t)b * OH + p) * OW + qb) * 64 + nt * 16 + ml;
                #pragma unroll
                for (int r = 0; r < 4; ++r)
                    if (qb + r < OW) op[(size_t)r * 64] = acc[mt][nt][r];
            }
        }
    }
}

extern "C" void kernel_launch(void* const* d_in, const int* in_sizes, int n_in,
                              void* d_out, int out_size, void* d_ws, size_t ws_size,
                              hipStream_t stream) {
    (void)in_sizes; (void)n_in; (void)out_size; (void)ws_size;
    const float* in   = (const float*)d_in[0];
    const float* kern = (const float*)d_in[1];
    float* out = (float*)d_out;
    __bf16* wsW = (__bf16*)d_ws;   // 36864 bf16 = 73728 B

    prep_w_kernel<<<144, 256, 0, stream>>>(kern, wsW);
    dim3 grid(17, 17, 8);          // q-tiles, p-tiles, batch
    tconv_kernel<<<grid, 512, 0, stream>>>(in, wsW, out);
}